// Round 1
// baseline (198.932 us; speedup 1.0000x reference)
//
#include <hip/hip_runtime.h>
#include <cstddef>

#define NEDGES   800000
#define NRAD     32
#define MAXZ     100
#define EPC      16                 // edges per chunk (per block iteration)
#define T1_OFF   0
#define T2_OFF   (MAXZ * 128)
#define WC_OFF   (2 * MAXZ * 128)

// ---------------------------------------------------------------------------
// Prep: fold the three weight blocks into small tables.
//   blocks 0..99   : T1[z][d] = b[d] + sum_k embed_w[z][k]*w_edge[k][d]
//                    T2[z][d] =        sum_k embed_w[z][k]*w_edge[128+k][d]
//   blocks 100..131: Wc[q][d] =        sum_m w_rbf[q][m]*w_edge[256+m][d]
// ---------------------------------------------------------------------------
__global__ __launch_bounds__(128)
void prep_kernel(const float* __restrict__ embed_w,
                 const float* __restrict__ w_rbf,
                 const float* __restrict__ w_edge,
                 const float* __restrict__ b_edge,
                 float* __restrict__ ws) {
    const int d = threadIdx.x;
    const int b = blockIdx.x;
    if (b < MAXZ) {
        float a1 = b_edge[d];
        float a2 = 0.f;
        #pragma unroll 8
        for (int k = 0; k < 128; ++k) {
            const float e = embed_w[b * 128 + k];
            a1 = fmaf(e, w_edge[k * 128 + d], a1);
            a2 = fmaf(e, w_edge[(128 + k) * 128 + d], a2);
        }
        ws[T1_OFF + b * 128 + d] = a1;
        ws[T2_OFF + b * 128 + d] = a2;
    } else {
        const int q = b - MAXZ;
        float a = 0.f;
        #pragma unroll 8
        for (int m = 0; m < 128; ++m)
            a = fmaf(w_rbf[q * 128 + m], w_edge[(256 + m) * 128 + d], a);
        ws[WC_OFF + q * 128 + d] = a;
    }
}

// ---------------------------------------------------------------------------
// Main: out[e] = silu( T1[x[idx_j[e]]] + T2[x[idx_i[e]]] + rbf[e] @ Wc )
// 256 threads: 32 column-groups (float4) x 8 edge-pairs -> 16 edges per chunk.
// ---------------------------------------------------------------------------
__global__ __launch_bounds__(256)
void edge_kernel(const int* __restrict__ x,
                 const float* __restrict__ rbf,
                 const int* __restrict__ idx_i,
                 const int* __restrict__ idx_j,
                 const float* __restrict__ ws,
                 float* __restrict__ out) {
    __shared__ float sWc[NRAD * 128];     // 16 KB, staged once per block
    __shared__ float sRbf[EPC * NRAD];    // 2 KB per chunk

    const float* __restrict__ T1 = ws + T1_OFF;
    const float* __restrict__ T2 = ws + T2_OFF;
    const float* __restrict__ Wc = ws + WC_OFF;

    const int tid = threadIdx.x;

    #pragma unroll
    for (int i = 0; i < (NRAD * 128) / 256; ++i)
        sWc[i * 256 + tid] = Wc[i * 256 + tid];

    const int c  = tid & 31;   // column group: d = 4*c .. 4*c+3
    const int ep = tid >> 5;   // edge pair 0..7 within chunk

    for (int base = blockIdx.x * EPC; base < NEDGES; base += gridDim.x * EPC) {
        __syncthreads();                        // sWc ready / sRbf safe to reuse
        const float* rb = rbf + (size_t)base * NRAD;
        sRbf[tid]       = rb[tid];
        sRbf[tid + 256] = rb[tid + 256];
        __syncthreads();

        const int e0 = base + ep * 2;
        const int e1 = e0 + 1;
        const int zj0 = x[idx_j[e0]];
        const int zi0 = x[idx_i[e0]];
        const int zj1 = x[idx_j[e1]];
        const int zi1 = x[idx_i[e1]];

        float4 a0 = *(const float4*)(T1 + zj0 * 128 + c * 4);
        float4 t0 = *(const float4*)(T2 + zi0 * 128 + c * 4);
        float4 a1 = *(const float4*)(T1 + zj1 * 128 + c * 4);
        float4 t1 = *(const float4*)(T2 + zi1 * 128 + c * 4);
        a0.x += t0.x; a0.y += t0.y; a0.z += t0.z; a0.w += t0.w;
        a1.x += t1.x; a1.y += t1.y; a1.z += t1.z; a1.w += t1.w;

        const float* __restrict__ rb0 = &sRbf[(ep * 2) * NRAD];
        const float* __restrict__ rb1 = &sRbf[(ep * 2 + 1) * NRAD];

        #pragma unroll
        for (int q = 0; q < NRAD; ++q) {
            const float4 w = *(const float4*)(&sWc[q * 128 + c * 4]);
            const float r0 = rb0[q];
            const float r1 = rb1[q];
            a0.x = fmaf(r0, w.x, a0.x);
            a0.y = fmaf(r0, w.y, a0.y);
            a0.z = fmaf(r0, w.z, a0.z);
            a0.w = fmaf(r0, w.w, a0.w);
            a1.x = fmaf(r1, w.x, a1.x);
            a1.y = fmaf(r1, w.y, a1.y);
            a1.z = fmaf(r1, w.z, a1.z);
            a1.w = fmaf(r1, w.w, a1.w);
        }

        float4 o0, o1;
        o0.x = a0.x / (1.f + __expf(-a0.x));
        o0.y = a0.y / (1.f + __expf(-a0.y));
        o0.z = a0.z / (1.f + __expf(-a0.z));
        o0.w = a0.w / (1.f + __expf(-a0.w));
        o1.x = a1.x / (1.f + __expf(-a1.x));
        o1.y = a1.y / (1.f + __expf(-a1.y));
        o1.z = a1.z / (1.f + __expf(-a1.z));
        o1.w = a1.w / (1.f + __expf(-a1.w));

        *(float4*)(out + (size_t)e0 * 128 + c * 4) = o0;
        *(float4*)(out + (size_t)e1 * 128 + c * 4) = o1;
    }
}

extern "C" void kernel_launch(void* const* d_in, const int* in_sizes, int n_in,
                              void* d_out, int out_size, void* d_ws, size_t ws_size,
                              hipStream_t stream) {
    const int*   x       = (const int*)d_in[0];
    const float* rbf     = (const float*)d_in[1];
    const int*   idx_i   = (const int*)d_in[2];
    const int*   idx_j   = (const int*)d_in[3];
    const float* embed_w = (const float*)d_in[4];
    const float* w_rbf   = (const float*)d_in[5];
    const float* w_edge  = (const float*)d_in[6];
    const float* b_edge  = (const float*)d_in[7];
    float* out = (float*)d_out;
    float* ws  = (float*)d_ws;

    prep_kernel<<<MAXZ + NRAD, 128, 0, stream>>>(embed_w, w_rbf, w_edge, b_edge, ws);
    edge_kernel<<<2048, 256, 0, stream>>>(x, rbf, idx_i, idx_j, ws, out);
}